// Round 1
// baseline (25.487 us; speedup 1.0000x reference)
//
#include <hip/hip_runtime.h>

// Embedding gather: out[b,s,:] = W[x[b,s],:]
// x: (B=4, S=4096) int32, W: (50257, 1024) f32, out: (4,4096,1024) f32.
// Pure memory-bound row gather. float4-vectorized, grid-stride.

#define D_MODEL 1024
#define D4 (D_MODEL / 4)   // 256 float4 per row

__global__ void embedding_gather_kernel(const int* __restrict__ x,
                                        const float4* __restrict__ W4,
                                        float4* __restrict__ out4,
                                        long long total4) {
    long long stride = (long long)gridDim.x * blockDim.x;
    for (long long t = (long long)blockIdx.x * blockDim.x + threadIdx.x;
         t < total4; t += stride) {
        long long row  = t >> 8;          // t / D4
        int       col  = (int)(t & (D4 - 1));
        long long widx = (long long)x[row] * D4 + col;
        out4[t] = W4[widx];
    }
}

extern "C" void kernel_launch(void* const* d_in, const int* in_sizes, int n_in,
                              void* d_out, int out_size, void* d_ws, size_t ws_size,
                              hipStream_t stream) {
    const int*    x   = (const int*)d_in[0];     // (B*S,)
    const float4* W4  = (const float4*)d_in[1];  // (VOCAB, D4)
    float4*       out = (float4*)d_out;

    long long total4 = (long long)out_size / 4;  // 16,777,216 / 4 = 4,194,304

    const int block = 256;
    long long nblocks = (total4 + block - 1) / block;
    int grid = (int)(nblocks < 2048 ? nblocks : 2048);

    embedding_gather_kernel<<<grid, block, 0, stream>>>(x, W4, out, total4);
}